// Round 11
// baseline (818.580 us; speedup 1.0000x reference)
//
#include <hip/hip_runtime.h>
#include <hip/hip_bf16.h>

#define NPIX   65536
#define TT     5
#define CC     10
#define HH     32
#define WIDTH  64
#define KW     32
#define OUTC   10

// ---- workspace layout (float offsets) ----
// LSTM weights k-major gate-packed for SGPR streaming: [k][j][g], g=(i,f,g,o)
#define OFF_L0I    0        // 1280  [c][j][g]
#define OFF_L0H    1280     // 4096  [k][j][g]
#define OFF_L1I    5376     // 4096
#define OFF_L1H    9472     // 4096
#define OFF_B0     13568    // 128   [j][g]
#define OFF_B1     13696    // 128
#define OFF_FC1W   13824    // 2048  [k][ch]
#define OFF_FC1B   15872    // 64
#define OFF_CWT2   16384    // 16384 [k][co2][ci] float2
#define OFF_CB     32768    // 256
#define OFF_FC2W2  33024    // 2048  [m2][ch] float2
#define OFF_FC2B   35072    // 32
#define OFF_FC3W4  35104    // 320   [oc2][m2] float4
#define OFF_FC3B   35424    // 16
#define OFF_GW     35440    // 8
#define OFF_FEATS_A 36864
#define OFF_FEATS_B (36864 + 8388608)

#define STRAIGHT_ATTR_IDX (65025 * 3)

__device__ __forceinline__ float sigf(float x)  { return 1.0f / (1.0f + __expf(-x)); }
__device__ __forceinline__ float tanhf_(float x){ return 1.0f - 2.0f / (__expf(2.0f * x) + 1.0f); }

// ---------------- prep: pack params ----------------
__global__ __launch_bounds__(256, 1)
void prep_kernel(const float* Wih0, const float* Whh0,
                 const float* bih0, const float* bhh0,
                 const float* Wih1, const float* Whh1,
                 const float* bih1, const float* bhh1,
                 const float* fc1w, const float* fc1b,
                 const float* convw, const float* convb,
                 const float* fc2w, const float* fc2b,
                 const float* fc3w, const float* fc3b,
                 const float* gparam, const float* eattr,
                 float* P) {
    int tid = blockIdx.x * blockDim.x + threadIdx.x;
    int stride = gridDim.x * blockDim.x;
    // LSTM k-major: [k][j][g] <- W[(g*32+j)*K + k]
    for (int idx = tid; idx < 1280; idx += stride) {
        int g = idx & 3, j = (idx >> 2) & 31, c = idx >> 7;
        P[OFF_L0I + idx] = Wih0[(g * 32 + j) * 10 + c];
    }
    for (int idx = tid; idx < 4096; idx += stride) {
        int g = idx & 3, j = (idx >> 2) & 31, k = idx >> 7;
        P[OFF_L0H + idx] = Whh0[(g * 32 + j) * 32 + k];
        P[OFF_L1I + idx] = Wih1[(g * 32 + j) * 32 + k];
        P[OFF_L1H + idx] = Whh1[(g * 32 + j) * 32 + k];
    }
    for (int idx = tid; idx < 128; idx += stride) {
        int g = idx & 3, j = idx >> 2;
        P[OFF_B0 + idx] = bih0[g * 32 + j] + bhh0[g * 32 + j];
        P[OFF_B1 + idx] = bih1[g * 32 + j] + bhh1[g * 32 + j];
    }
    // fc1 k-major [k][ch]
    for (int idx = tid; idx < 2048; idx += stride) {
        int ch = idx & 63, k = idx >> 6;
        P[OFF_FC1W + idx] = fc1w[ch * 32 + k];
    }
    for (int i = tid; i < 64; i += stride) P[OFF_FC1B + i] = fc1b[i];
    // conv [k][co2][ci] float2
    for (int idx = tid; idx < 16384; idx += stride) {
        int k = idx >> 12, r = idx & 4095, e = r >> 1, h = r & 1;
        int co2 = e >> 6, ci = e & 63;
        P[OFF_CWT2 + idx] = convw[k * 4096 + ci * 64 + (2 * co2 + h)];
    }
    for (int i = tid; i < 256; i += stride) P[OFF_CB + i] = convb[i];
    for (int idx = tid; idx < 2048; idx += stride) {
        int e = idx >> 1, h = idx & 1, m2 = e >> 6, ch = e & 63;
        P[OFF_FC2W2 + idx] = fc2w[(2 * m2 + h) * 64 + ch];
    }
    for (int i = tid; i < 32;  i += stride) P[OFF_FC2B + i] = fc2b[i];
    for (int idx = tid; idx < 320; idx += stride) {
        int q = idx & 3, e = idx >> 2, oc2 = e >> 4, m2 = e & 15;
        int oc = 2 * oc2 + (q & 1), m = 2 * m2 + (q >> 1);
        P[OFF_FC3W4 + idx] = fc3w[oc * 32 + m];
    }
    for (int i = tid; i < 10; i += stride) P[OFF_FC3B + i] = fc3b[i];
    for (int idx = tid; idx < 8; idx += stride) {
        int k = idx >> 1;
        float g = gparam[k];
        float denom = g * g + 1e-8f;
        float a = (idx & 1) ? eattr[0] : eattr[STRAIGHT_ATTR_IDX];
        P[OFF_GW + idx] = __expf(-(a * a) / denom);
    }
}

// ---------------- LSTM: 4-way wave j-split (R7 exact — 328us control) ----------------
// Settled findings R0-R9: the SGPR-weight v_fma stream costs ~4 issue-cyc/FMA
// intrinsically (R9: forcing arch-VGPR accumulators [VGPR 168] left per-wave
// busy unchanged -> NOT an AGPR-companion tax). launch_bounds arg2 MUST stay 1
// (arg 4 -> 64-VGPR cap spill disaster R1/R2; arg 2 inert R8). AGPR clobber
// (R9) kills occupancy -> never. This kernel is at its structural floor.
#define ROW_ACC32(WBASE, SVAL) do {                                 \
    const float* wr_ = (WBASE); float sv_ = (SVAL);                 \
    _Pragma("unroll")                                               \
    for (int q_ = 0; q_ < 32; q_++)                                 \
        z[q_] = __builtin_fmaf(wr_[q_], sv_, z[q_]);                \
    } while (0)

__global__ __launch_bounds__(256, 1)
void lstm_fc1_kernel(const float* __restrict__ x,
                     const float* __restrict__ P,
                     float* __restrict__ feats) {
    __shared__ float H0[HH * 64];    // 8192 B  [j][lane]
    __shared__ float H1[HH * 64];    // 8192 B  (total 16384)

    int tid  = threadIdx.x;
    int w    = __builtin_amdgcn_readfirstlane(tid >> 6);  // wave id 0..3
    int lane = tid & 63;             // pixel column within block
    int jw   = w << 3;               // first owned unit (0,8,16,24)
    int w32  = w << 5;               // float offset into 128-wide gate rows

    int n = blockIdx.x * 64 + lane;
    int b = n >> 16;
    int pix = n & (NPIX - 1);
    const float* xb = x + (size_t)b * TT * CC * NPIX + pix;

    float c0[8], c1[8];
#pragma unroll
    for (int j = 0; j < 8; j++) {
        c0[j] = 0.f; c1[j] = 0.f;
        H0[(jw + j) * 64 + lane] = 0.f;
        H1[(jw + j) * 64 + lane] = 0.f;
    }
    __syncthreads();

#pragma unroll 1
    for (int t = 0; t < TT; t++) {
        float xcur[CC];
#pragma unroll
        for (int c = 0; c < CC; c++)
            xcur[c] = xb[(size_t)(t * CC + c) * NPIX];

        // ---- layer 0 ----
        {
            float z[32];             // [j_local*4+g], g=(i,f,g,o)
            const float* bb = P + OFF_B0 + w32;
#pragma unroll
            for (int q = 0; q < 32; q++) z[q] = bb[q];
#pragma unroll 1
            for (int c = 0; c < CC; c++)
                ROW_ACC32(P + OFF_L0I + c * 128 + w32, xcur[c]);
#pragma unroll 1
            for (int k = 0; k < HH; k++) {
                float hv = H0[k * 64 + lane];     // h0(t-1)
                ROW_ACC32(P + OFF_L0H + k * 128 + w32, hv);
            }
            __syncthreads();                      // all waves done reading old H0
#pragma unroll
            for (int j = 0; j < 8; j++) {
                float cn = sigf(z[4 * j + 1]) * c0[j]
                         + sigf(z[4 * j + 0]) * tanhf_(z[4 * j + 2]);
                c0[j] = cn;
                H0[(jw + j) * 64 + lane] = sigf(z[4 * j + 3]) * tanhf_(cn);
            }
            __syncthreads();                      // new H0 visible
        }

        // ---- layer 1 ----
        {
            float z[32];
            const float* bb = P + OFF_B1 + w32;
#pragma unroll
            for (int q = 0; q < 32; q++) z[q] = bb[q];
#pragma unroll 1
            for (int k = 0; k < HH; k++) {
                float hv = H0[k * 64 + lane];     // h0(t)
                ROW_ACC32(P + OFF_L1I + k * 128 + w32, hv);
            }
#pragma unroll 1
            for (int k = 0; k < HH; k++) {
                float hv = H1[k * 64 + lane];     // h1(t-1)
                ROW_ACC32(P + OFF_L1H + k * 128 + w32, hv);
            }
            __syncthreads();                      // all waves done reading old H1
#pragma unroll
            for (int j = 0; j < 8; j++) {
                float cn = sigf(z[4 * j + 1]) * c1[j]
                         + sigf(z[4 * j + 0]) * tanhf_(z[4 * j + 2]);
                c1[j] = cn;
                H1[(jw + j) * 64 + lane] = sigf(z[4 * j + 3]) * tanhf_(cn);
            }
            __syncthreads();                      // new H1 visible
        }
    }

    // ---- fc1 + relu: wave w computes ch in [16w, 16w+16) ----
    float f[16];
    {
        const float* fb1 = P + OFF_FC1B + (w << 4);
#pragma unroll
        for (int m = 0; m < 16; m++) f[m] = fb1[m];
    }
#pragma unroll 1
    for (int k = 0; k < HH; k++) {
        float hv = H1[k * 64 + lane];
        const float* wr = P + OFF_FC1W + k * 64 + (w << 4);
#pragma unroll
        for (int m = 0; m < 16; m++)
            f[m] = __builtin_fmaf(wr[m], hv, f[m]);
    }
    float* fob = feats + (size_t)b * WIDTH * NPIX + (size_t)(w * 16) * NPIX + pix;
#pragma unroll
    for (int m = 0; m < 16; m++)
        fob[(size_t)m * NPIX] = fmaxf(f[m], 0.f);
}

// ---------------- fused conv layer: SMEM weight streaming (no LDS) ----------------
// R10 finding: doubling waves/SIMD did NOT speed conv -> not latency-bound.
// Model: the GEMM re-read the whole 16KB weight matrix from LDS per pixel
// (1024 ds_read_b128/thread); broadcast reads still pay full LDS return-path
// BW (1KB/inst) -> ~8.4MB LDS traffic per CU ~= 31us/layer, the dominant cost.
// Fix: weights are block-uniform -> read straight from P; compiler scalarizes
// uniform addresses to s_load + v_fma with SGPR operand (the lstm mechanism),
// moving the stream to the scalar pipe (cached, shared by all waves). Bit-
// identical values and FMA order -> absmax unchanged. No LDS, no barrier.
__global__ __launch_bounds__(256, 1)
void conv_fused_kernel(const float* __restrict__ Fin, float* __restrict__ Fout,
                       const float* __restrict__ P, int k) {
    int n = blockIdx.x * 256 + threadIdx.x;
    int b = n >> 16;
    int pix = n & (NPIX - 1);
    int i = pix >> 8, j = pix & 255;
    float wstr = P[OFF_GW + 2 * k], wdiag = P[OFF_GW + 2 * k + 1];
    float fu = (i > 0) ? wstr : 0.f, fd = (i < 255) ? wstr : 0.f;
    float fl = (j > 0) ? wstr : 0.f, fr = (j < 255) ? wstr : 0.f;
    float ful = (i > 0 && j > 0) ? wdiag : 0.f, fur = (i > 0 && j < 255) ? wdiag : 0.f;
    float fdl = (i < 255 && j > 0) ? wdiag : 0.f, fdr = (i < 255 && j < 255) ? wdiag : 0.f;

    const float* fb = Fin + (size_t)b * WIDTH * NPIX + pix;
    float u[WIDTH];
#pragma unroll
    for (int ch = 0; ch < WIDTH; ch++) {
        const float* yc = fb + (size_t)ch * NPIX;
        float v = yc[0];
        v += fu * yc[-256] + fd * yc[256] + fl * yc[-1] + fr * yc[1];
        v += ful * yc[-257] + fur * yc[-255] + fdl * yc[255] + fdr * yc[257];
        u[ch] = v;
    }

    const float4* cw = (const float4*)(P + OFF_CWT2 + k * 4096);  // uniform -> s_load
    const float*  cb = P + OFF_CB + k * 64;

    float* ob = Fout + (size_t)b * WIDTH * NPIX + pix;
#pragma unroll 1
    for (int co2 = 0; co2 < 32; co2++) {
        float ax = cb[2 * co2], ay = cb[2 * co2 + 1];
        const float4* wv = cw + co2 * 32;
#pragma unroll
        for (int ci2 = 0; ci2 < 32; ci2++) {
            float4 q = wv[ci2];
            float a0 = u[2 * ci2], a1 = u[2 * ci2 + 1];
            ax = __builtin_fmaf(q.x, a0, ax); ax = __builtin_fmaf(q.z, a1, ax);
            ay = __builtin_fmaf(q.y, a0, ay); ay = __builtin_fmaf(q.w, a1, ay);
        }
        ob[(size_t)(2 * co2) * NPIX]     = fmaxf(ax, 0.f);
        ob[(size_t)(2 * co2 + 1) * NPIX] = fmaxf(ay, 0.f);
    }
}

// ---------------- last conv (no relu) + fc2/fc3 head: SMEM weight streaming ----------------
__global__ __launch_bounds__(256, 1)
void conv_head_kernel(const float* __restrict__ Fin, const float* __restrict__ P,
                      float* __restrict__ out) {
    const int k = 3;
    int n = blockIdx.x * 256 + threadIdx.x;
    int b = n >> 16;
    int pix = n & (NPIX - 1);
    int i = pix >> 8, j = pix & 255;
    float wstr = P[OFF_GW + 2 * k], wdiag = P[OFF_GW + 2 * k + 1];
    float fu = (i > 0) ? wstr : 0.f, fd = (i < 255) ? wstr : 0.f;
    float fl = (j > 0) ? wstr : 0.f, fr = (j < 255) ? wstr : 0.f;
    float ful = (i > 0 && j > 0) ? wdiag : 0.f, fur = (i > 0 && j < 255) ? wdiag : 0.f;
    float fdl = (i < 255 && j > 0) ? wdiag : 0.f, fdr = (i < 255 && j < 255) ? wdiag : 0.f;

    const float* fb = Fin + (size_t)b * WIDTH * NPIX + pix;
    float u[WIDTH];
#pragma unroll
    for (int ch = 0; ch < WIDTH; ch++) {
        const float* yc = fb + (size_t)ch * NPIX;
        float v = yc[0];
        v += fu * yc[-256] + fd * yc[256] + fl * yc[-1] + fr * yc[1];
        v += ful * yc[-257] + fur * yc[-255] + fdl * yc[255] + fdr * yc[257];
        u[ch] = v;
    }

    const float4* cw3 = (const float4*)(P + OFF_CWT2 + k * 4096);  // uniform -> s_load
    const float*  cb3 = P + OFF_CB + k * 64;

    float f[WIDTH];
#pragma unroll 1
    for (int co2 = 0; co2 < 32; co2++) {
        float ax = cb3[2 * co2], ay = cb3[2 * co2 + 1];
        const float4* wv = cw3 + co2 * 32;
#pragma unroll
        for (int ci2 = 0; ci2 < 32; ci2++) {
            float4 q = wv[ci2];
            float a0 = u[2 * ci2], a1 = u[2 * ci2 + 1];
            ax = __builtin_fmaf(q.x, a0, ax); ax = __builtin_fmaf(q.z, a1, ax);
            ay = __builtin_fmaf(q.y, a0, ay); ay = __builtin_fmaf(q.w, a1, ay);
        }
        f[2 * co2] = ax; f[2 * co2 + 1] = ay;
    }

    const float4* f2w = (const float4*)(P + OFF_FC2W2);
    const float*  f2b = P + OFF_FC2B;
    const float4* f3w = (const float4*)(P + OFF_FC3W4);
    const float*  f3b = P + OFF_FC3B;

    float2 oo[5];
#pragma unroll
    for (int oc2 = 0; oc2 < 5; oc2++) oo[oc2] = make_float2(f3b[2 * oc2], f3b[2 * oc2 + 1]);
#pragma unroll 1
    for (int m2 = 0; m2 < 16; m2++) {
        float ax = f2b[2 * m2], ay = f2b[2 * m2 + 1];
        const float4* wv = f2w + m2 * 32;
#pragma unroll
        for (int ch2 = 0; ch2 < 32; ch2++) {
            float4 q = wv[ch2];
            ax = __builtin_fmaf(q.x, f[2 * ch2], ax); ax = __builtin_fmaf(q.z, f[2 * ch2 + 1], ax);
            ay = __builtin_fmaf(q.y, f[2 * ch2], ay); ay = __builtin_fmaf(q.w, f[2 * ch2 + 1], ay);
        }
        ax = fmaxf(ax, 0.f); ay = fmaxf(ay, 0.f);
#pragma unroll
        for (int oc2 = 0; oc2 < 5; oc2++) {
            float4 q = f3w[oc2 * 16 + m2];
            oo[oc2].x += q.x * ax + q.z * ay;
            oo[oc2].y += q.y * ax + q.w * ay;
        }
    }
    float* ob = out + (size_t)b * OUTC * NPIX + pix;
#pragma unroll
    for (int oc2 = 0; oc2 < 5; oc2++) {
        ob[(size_t)(2 * oc2) * NPIX]     = oo[oc2].x;
        ob[(size_t)(2 * oc2 + 1) * NPIX] = oo[oc2].y;
    }
}

extern "C" void kernel_launch(void* const* d_in, const int* in_sizes, int n_in,
                              void* d_out, int out_size, void* d_ws, size_t ws_size,
                              hipStream_t stream) {
    const float* x     = (const float*)d_in[0];
    const float* eattr = (const float*)d_in[3];
    const float* Wih0  = (const float*)d_in[4];
    const float* Whh0  = (const float*)d_in[5];
    const float* bih0  = (const float*)d_in[6];
    const float* bhh0  = (const float*)d_in[7];
    const float* Wih1  = (const float*)d_in[8];
    const float* Whh1  = (const float*)d_in[9];
    const float* bih1  = (const float*)d_in[10];
    const float* bhh1  = (const float*)d_in[11];
    const float* fc1w  = (const float*)d_in[12];
    const float* fc1b  = (const float*)d_in[13];
    const float* convw = (const float*)d_in[14];
    const float* convb = (const float*)d_in[15];
    const float* gparam= (const float*)d_in[16];
    const float* fc2w  = (const float*)d_in[17];
    const float* fc2b  = (const float*)d_in[18];
    const float* fc3w  = (const float*)d_in[19];
    const float* fc3b  = (const float*)d_in[20];

    float* P  = (float*)d_ws;
    float* FA = P + OFF_FEATS_A;
    float* FB = P + OFF_FEATS_B;

    prep_kernel<<<64, 256, 0, stream>>>(Wih0, Whh0, bih0, bhh0, Wih1, Whh1, bih1, bhh1,
                                        fc1w, fc1b, convw, convb, fc2w, fc2b, fc3w, fc3b,
                                        gparam, eattr, P);
    lstm_fc1_kernel<<<2048, 256, 0, stream>>>(x, P, FA);
    conv_fused_kernel<<<512, 256, 0, stream>>>(FA, FB, P, 0);
    conv_fused_kernel<<<512, 256, 0, stream>>>(FB, FA, P, 1);
    conv_fused_kernel<<<512, 256, 0, stream>>>(FA, FB, P, 2);
    conv_head_kernel<<<512, 256, 0, stream>>>(FB, P, (float*)d_out);
}

// Round 12
// 566.006 us; speedup vs baseline: 1.4462x; 1.4462x over previous
//
#include <hip/hip_runtime.h>
#include <hip/hip_bf16.h>

#define NPIX   65536
#define TT     5
#define CC     10
#define HH     32
#define WIDTH  64
#define KW     32
#define OUTC   10

// ---- workspace layout (float offsets) ----
// LSTM weights k-major gate-packed for SGPR streaming: [k][j][g], g=(i,f,g,o)
#define OFF_L0I    0        // 1280  [c][j][g]
#define OFF_L0H    1280     // 4096  [k][j][g]
#define OFF_L1I    5376     // 4096
#define OFF_L1H    9472     // 4096
#define OFF_B0     13568    // 128   [j][g]
#define OFF_B1     13696    // 128
#define OFF_FC1W   13824    // 2048  [k][ch]
#define OFF_FC1B   15872    // 64
#define OFF_CWT2   16384    // 16384 [k][ci][co]  (straight copy of conv_w)
#define OFF_CB     32768    // 256
#define OFF_FC2W2  33024    // 2048  [m2][ch] float2
#define OFF_FC2B   35072    // 32
#define OFF_FC3W4  35104    // 320   [oc2][m2] float4
#define OFF_FC3B   35424    // 16
#define OFF_GW     35440    // 8
#define OFF_FEATS_A 36864
#define OFF_FEATS_B (36864 + 8388608)

#define STRAIGHT_ATTR_IDX (65025 * 3)

__device__ __forceinline__ float sigf(float x)  { return 1.0f / (1.0f + __expf(-x)); }
__device__ __forceinline__ float tanhf_(float x){ return 1.0f - 2.0f / (__expf(2.0f * x) + 1.0f); }

// ---------------- prep: pack params ----------------
__global__ __launch_bounds__(256, 1)
void prep_kernel(const float* Wih0, const float* Whh0,
                 const float* bih0, const float* bhh0,
                 const float* Wih1, const float* Whh1,
                 const float* bih1, const float* bhh1,
                 const float* fc1w, const float* fc1b,
                 const float* convw, const float* convb,
                 const float* fc2w, const float* fc2b,
                 const float* fc3w, const float* fc3b,
                 const float* gparam, const float* eattr,
                 float* P) {
    int tid = blockIdx.x * blockDim.x + threadIdx.x;
    int stride = gridDim.x * blockDim.x;
    // LSTM k-major: [k][j][g] <- W[(g*32+j)*K + k]
    for (int idx = tid; idx < 1280; idx += stride) {
        int g = idx & 3, j = (idx >> 2) & 31, c = idx >> 7;
        P[OFF_L0I + idx] = Wih0[(g * 32 + j) * 10 + c];
    }
    for (int idx = tid; idx < 4096; idx += stride) {
        int g = idx & 3, j = (idx >> 2) & 31, k = idx >> 7;
        P[OFF_L0H + idx] = Whh0[(g * 32 + j) * 32 + k];
        P[OFF_L1I + idx] = Wih1[(g * 32 + j) * 32 + k];
        P[OFF_L1H + idx] = Whh1[(g * 32 + j) * 32 + k];
    }
    for (int idx = tid; idx < 128; idx += stride) {
        int g = idx & 3, j = idx >> 2;
        P[OFF_B0 + idx] = bih0[g * 32 + j] + bhh0[g * 32 + j];
        P[OFF_B1 + idx] = bih1[g * 32 + j] + bhh1[g * 32 + j];
    }
    // fc1 k-major [k][ch]
    for (int idx = tid; idx < 2048; idx += stride) {
        int ch = idx & 63, k = idx >> 6;
        P[OFF_FC1W + idx] = fc1w[ch * 32 + k];
    }
    for (int i = tid; i < 64; i += stride) P[OFF_FC1B + i] = fc1b[i];
    // conv: straight copy, [k][ci][co] (convw native layout)
    for (int idx = tid; idx < 16384; idx += stride)
        P[OFF_CWT2 + idx] = convw[idx];
    for (int i = tid; i < 256; i += stride) P[OFF_CB + i] = convb[i];
    for (int idx = tid; idx < 2048; idx += stride) {
        int e = idx >> 1, h = idx & 1, m2 = e >> 6, ch = e & 63;
        P[OFF_FC2W2 + idx] = fc2w[(2 * m2 + h) * 64 + ch];
    }
    for (int i = tid; i < 32;  i += stride) P[OFF_FC2B + i] = fc2b[i];
    for (int idx = tid; idx < 320; idx += stride) {
        int q = idx & 3, e = idx >> 2, oc2 = e >> 4, m2 = e & 15;
        int oc = 2 * oc2 + (q & 1), m = 2 * m2 + (q >> 1);
        P[OFF_FC3W4 + idx] = fc3w[oc * 32 + m];
    }
    for (int i = tid; i < 10; i += stride) P[OFF_FC3B + i] = fc3b[i];
    for (int idx = tid; idx < 8; idx += stride) {
        int k = idx >> 1;
        float g = gparam[k];
        float denom = g * g + 1e-8f;
        float a = (idx & 1) ? eattr[0] : eattr[STRAIGHT_ATTR_IDX];
        P[OFF_GW + idx] = __expf(-(a * a) / denom);
    }
}

// ---------------- LSTM: 4-way wave j-split (R7 exact — ~326us control) ----------------
// Settled R0-R9: SGPR-weight v_fma stream ~4 issue-cyc/FMA intrinsic; arg2
// of launch_bounds must stay 1; no AGPR clobbers. Structural floor reached.
#define ROW_ACC32(WBASE, SVAL) do {                                 \
    const float* wr_ = (WBASE); float sv_ = (SVAL);                 \
    _Pragma("unroll")                                               \
    for (int q_ = 0; q_ < 32; q_++)                                 \
        z[q_] = __builtin_fmaf(wr_[q_], sv_, z[q_]);                \
    } while (0)

__global__ __launch_bounds__(256, 1)
void lstm_fc1_kernel(const float* __restrict__ x,
                     const float* __restrict__ P,
                     float* __restrict__ feats) {
    __shared__ float H0[HH * 64];    // 8192 B  [j][lane]
    __shared__ float H1[HH * 64];    // 8192 B  (total 16384)

    int tid  = threadIdx.x;
    int w    = __builtin_amdgcn_readfirstlane(tid >> 6);  // wave id 0..3
    int lane = tid & 63;             // pixel column within block
    int jw   = w << 3;               // first owned unit (0,8,16,24)
    int w32  = w << 5;               // float offset into 128-wide gate rows

    int n = blockIdx.x * 64 + lane;
    int b = n >> 16;
    int pix = n & (NPIX - 1);
    const float* xb = x + (size_t)b * TT * CC * NPIX + pix;

    float c0[8], c1[8];
#pragma unroll
    for (int j = 0; j < 8; j++) {
        c0[j] = 0.f; c1[j] = 0.f;
        H0[(jw + j) * 64 + lane] = 0.f;
        H1[(jw + j) * 64 + lane] = 0.f;
    }
    __syncthreads();

#pragma unroll 1
    for (int t = 0; t < TT; t++) {
        float xcur[CC];
#pragma unroll
        for (int c = 0; c < CC; c++)
            xcur[c] = xb[(size_t)(t * CC + c) * NPIX];

        // ---- layer 0 ----
        {
            float z[32];             // [j_local*4+g], g=(i,f,g,o)
            const float* bb = P + OFF_B0 + w32;
#pragma unroll
            for (int q = 0; q < 32; q++) z[q] = bb[q];
#pragma unroll 1
            for (int c = 0; c < CC; c++)
                ROW_ACC32(P + OFF_L0I + c * 128 + w32, xcur[c]);
#pragma unroll 1
            for (int k = 0; k < HH; k++) {
                float hv = H0[k * 64 + lane];     // h0(t-1)
                ROW_ACC32(P + OFF_L0H + k * 128 + w32, hv);
            }
            __syncthreads();                      // all waves done reading old H0
#pragma unroll
            for (int j = 0; j < 8; j++) {
                float cn = sigf(z[4 * j + 1]) * c0[j]
                         + sigf(z[4 * j + 0]) * tanhf_(z[4 * j + 2]);
                c0[j] = cn;
                H0[(jw + j) * 64 + lane] = sigf(z[4 * j + 3]) * tanhf_(cn);
            }
            __syncthreads();                      // new H0 visible
        }

        // ---- layer 1 ----
        {
            float z[32];
            const float* bb = P + OFF_B1 + w32;
#pragma unroll
            for (int q = 0; q < 32; q++) z[q] = bb[q];
#pragma unroll 1
            for (int k = 0; k < HH; k++) {
                float hv = H0[k * 64 + lane];     // h0(t)
                ROW_ACC32(P + OFF_L1I + k * 128 + w32, hv);
            }
#pragma unroll 1
            for (int k = 0; k < HH; k++) {
                float hv = H1[k * 64 + lane];     // h1(t-1)
                ROW_ACC32(P + OFF_L1H + k * 128 + w32, hv);
            }
            __syncthreads();                      // all waves done reading old H1
#pragma unroll
            for (int j = 0; j < 8; j++) {
                float cn = sigf(z[4 * j + 1]) * c1[j]
                         + sigf(z[4 * j + 0]) * tanhf_(z[4 * j + 2]);
                c1[j] = cn;
                H1[(jw + j) * 64 + lane] = sigf(z[4 * j + 3]) * tanhf_(cn);
            }
            __syncthreads();                      // new H1 visible
        }
    }

    // ---- fc1 + relu: wave w computes ch in [16w, 16w+16) ----
    float f[16];
    {
        const float* fb1 = P + OFF_FC1B + (w << 4);
#pragma unroll
        for (int m = 0; m < 16; m++) f[m] = fb1[m];
    }
#pragma unroll 1
    for (int k = 0; k < HH; k++) {
        float hv = H1[k * 64 + lane];
        const float* wr = P + OFF_FC1W + k * 64 + (w << 4);
#pragma unroll
        for (int m = 0; m < 16; m++)
            f[m] = __builtin_fmaf(wr[m], hv, f[m]);
    }
    float* fob = feats + (size_t)b * WIDTH * NPIX + (size_t)(w * 16) * NPIX + pix;
#pragma unroll
    for (int m = 0; m < 16; m++)
        fob[(size_t)m * NPIX] = fmaxf(f[m], 0.f);
}

// ---------------- fused conv layer: U-in-LDS, 4 px x 16 outs per lane ----------------
// R10/R11 bracketing: conv GEMM is LDS-return-BW bound on weight re-reads
// (1024 ds_read_b128/lane ~= 41us of 62); occupancy doubling (R10) and
// P-direct weights (R11) both regress. Fix: amortize W reads over 4 px/lane.
// Phase 1: stencil -> US[64][256] in LDS (low reg pressure, conflict-free).
// Phase 2: wave w owns outputs [16w,16w+16); lane l owns px [4l,4l+4);
//   per ci: 1 b128 U-read + 4 b128 broadcast W-reads -> 320 b128/lane (3.2x
//   less LDS traffic), same 4096 FMA, float4 stores. Per-output accumulation
//   is ci-ascending like R8 -> bit-identical. US+CW = 80KB -> 2 blocks/CU.
__global__ __launch_bounds__(256, 1)
void conv_fused_kernel(const float* __restrict__ Fin, float* __restrict__ Fout,
                       const float* __restrict__ P, int k) {
    __shared__ float US[64 * 256];   // 65536 B  [ci][px]
    __shared__ float CW[64 * 64];    // 16384 B  [ci][co]

    int tid = threadIdx.x;
    {
        const float4* src = (const float4*)(P + OFF_CWT2 + k * 4096);
        float4* dst = (float4*)CW;
        for (int idx = tid; idx < 1024; idx += 256) dst[idx] = src[idx];
    }

    int n = blockIdx.x * 256 + tid;
    int b = n >> 16;
    int pix = n & (NPIX - 1);
    int i = pix >> 8, j = pix & 255;
    float wstr = P[OFF_GW + 2 * k], wdiag = P[OFF_GW + 2 * k + 1];
    float fu = (i > 0) ? wstr : 0.f, fd = (i < 255) ? wstr : 0.f;
    float fl = (j > 0) ? wstr : 0.f, fr = (j < 255) ? wstr : 0.f;
    float ful = (i > 0 && j > 0) ? wdiag : 0.f, fur = (i > 0 && j < 255) ? wdiag : 0.f;
    float fdl = (i < 255 && j > 0) ? wdiag : 0.f, fdr = (i < 255 && j < 255) ? wdiag : 0.f;

    const float* fb = Fin + (size_t)b * WIDTH * NPIX + pix;
#pragma unroll
    for (int ch = 0; ch < WIDTH; ch++) {
        const float* yc = fb + (size_t)ch * NPIX;
        float v = yc[0];
        v += fu * yc[-256] + fd * yc[256] + fl * yc[-1] + fr * yc[1];
        v += ful * yc[-257] + fur * yc[-255] + fdl * yc[255] + fdr * yc[257];
        US[ch * 256 + tid] = v;
    }
    __syncthreads();

    int l = tid & 63;
    int ob16 = (tid >> 6) << 4;          // wave's first output channel
    float4 acc[16];
#pragma unroll
    for (int o = 0; o < 16; o++) {
        float bv = P[OFF_CB + k * 64 + ob16 + o];
        acc[o] = make_float4(bv, bv, bv, bv);
    }
    const float4* US4 = (const float4*)US;
#pragma unroll 1
    for (int ci = 0; ci < 64; ci++) {
        float4 u4 = US4[ci * 64 + l];
        const float4* wr4 = (const float4*)(CW + ci * 64 + ob16);
#pragma unroll
        for (int q = 0; q < 4; q++) {
            float4 wq = wr4[q];
            acc[4 * q + 0].x = __builtin_fmaf(wq.x, u4.x, acc[4 * q + 0].x);
            acc[4 * q + 0].y = __builtin_fmaf(wq.x, u4.y, acc[4 * q + 0].y);
            acc[4 * q + 0].z = __builtin_fmaf(wq.x, u4.z, acc[4 * q + 0].z);
            acc[4 * q + 0].w = __builtin_fmaf(wq.x, u4.w, acc[4 * q + 0].w);
            acc[4 * q + 1].x = __builtin_fmaf(wq.y, u4.x, acc[4 * q + 1].x);
            acc[4 * q + 1].y = __builtin_fmaf(wq.y, u4.y, acc[4 * q + 1].y);
            acc[4 * q + 1].z = __builtin_fmaf(wq.y, u4.z, acc[4 * q + 1].z);
            acc[4 * q + 1].w = __builtin_fmaf(wq.y, u4.w, acc[4 * q + 1].w);
            acc[4 * q + 2].x = __builtin_fmaf(wq.z, u4.x, acc[4 * q + 2].x);
            acc[4 * q + 2].y = __builtin_fmaf(wq.z, u4.y, acc[4 * q + 2].y);
            acc[4 * q + 2].z = __builtin_fmaf(wq.z, u4.z, acc[4 * q + 2].z);
            acc[4 * q + 2].w = __builtin_fmaf(wq.z, u4.w, acc[4 * q + 2].w);
            acc[4 * q + 3].x = __builtin_fmaf(wq.w, u4.x, acc[4 * q + 3].x);
            acc[4 * q + 3].y = __builtin_fmaf(wq.w, u4.y, acc[4 * q + 3].y);
            acc[4 * q + 3].z = __builtin_fmaf(wq.w, u4.z, acc[4 * q + 3].z);
            acc[4 * q + 3].w = __builtin_fmaf(wq.w, u4.w, acc[4 * q + 3].w);
        }
    }

    int pn = blockIdx.x * 256 + 4 * l;   // first of this lane's 4 pixels
    int pb = pn >> 16;
    int ppix = pn & (NPIX - 1);
    float* ob = Fout + (size_t)pb * WIDTH * NPIX + ppix;
#pragma unroll
    for (int o = 0; o < 16; o++) {
        float4 r;
        r.x = fmaxf(acc[o].x, 0.f); r.y = fmaxf(acc[o].y, 0.f);
        r.z = fmaxf(acc[o].z, 0.f); r.w = fmaxf(acc[o].w, 0.f);
        *(float4*)(ob + (size_t)(ob16 + o) * NPIX) = r;
    }
}

// ---------------- last conv (no relu) + fc2/fc3 head (R8 math; gathers old
// float2 weight layout from the new [ci][co] CWT2 during staging) ----------------
__global__ __launch_bounds__(256, 1)
void conv_head_kernel(const float* __restrict__ Fin, const float* __restrict__ P,
                      float* __restrict__ out) {
    const int k = 3;
    __shared__ float4 CW3[1024];
    __shared__ float  CB3[64];
    __shared__ float4 F2W[512];
    __shared__ float  F2B[32];
    __shared__ float4 F3W[80];
    __shared__ float  F3B[12];
    {
        const float* wsrc = P + OFF_CWT2 + k * 4096;   // [ci][co]
        for (int idx = threadIdx.x; idx < 1024; idx += 256) {
            int co2 = idx >> 5, ci2 = idx & 31;
            CW3[idx] = make_float4(wsrc[(2 * ci2) * 64 + 2 * co2],
                                   wsrc[(2 * ci2) * 64 + 2 * co2 + 1],
                                   wsrc[(2 * ci2 + 1) * 64 + 2 * co2],
                                   wsrc[(2 * ci2 + 1) * 64 + 2 * co2 + 1]);
        }
        const float4* s2 = (const float4*)(P + OFF_FC2W2);
        for (int i = threadIdx.x; i < 512; i += 256) F2W[i] = s2[i];
        const float4* s3 = (const float4*)(P + OFF_FC3W4);
        if (threadIdx.x < 80) F3W[threadIdx.x] = s3[threadIdx.x];
        if (threadIdx.x < 64) CB3[threadIdx.x] = P[OFF_CB + k * 64 + threadIdx.x];
        if (threadIdx.x < 32) F2B[threadIdx.x] = P[OFF_FC2B + threadIdx.x];
        if (threadIdx.x < 10) F3B[threadIdx.x] = P[OFF_FC3B + threadIdx.x];
    }
    __syncthreads();

    int n = blockIdx.x * 256 + threadIdx.x;
    int b = n >> 16;
    int pix = n & (NPIX - 1);
    int i = pix >> 8, j = pix & 255;
    float wstr = P[OFF_GW + 2 * k], wdiag = P[OFF_GW + 2 * k + 1];
    float fu = (i > 0) ? wstr : 0.f, fd = (i < 255) ? wstr : 0.f;
    float fl = (j > 0) ? wstr : 0.f, fr = (j < 255) ? wstr : 0.f;
    float ful = (i > 0 && j > 0) ? wdiag : 0.f, fur = (i > 0 && j < 255) ? wdiag : 0.f;
    float fdl = (i < 255 && j > 0) ? wdiag : 0.f, fdr = (i < 255 && j < 255) ? wdiag : 0.f;

    const float* fb = Fin + (size_t)b * WIDTH * NPIX + pix;
    float u[WIDTH];
#pragma unroll
    for (int ch = 0; ch < WIDTH; ch++) {
        const float* yc = fb + (size_t)ch * NPIX;
        float v = yc[0];
        v += fu * yc[-256] + fd * yc[256] + fl * yc[-1] + fr * yc[1];
        v += ful * yc[-257] + fur * yc[-255] + fdl * yc[255] + fdr * yc[257];
        u[ch] = v;
    }

    float f[WIDTH];
#pragma unroll
    for (int co2 = 0; co2 < 32; co2++) {
        float ax = CB3[2 * co2], ay = CB3[2 * co2 + 1];
        const float4* wv = CW3 + co2 * 32;
#pragma unroll
        for (int ci2 = 0; ci2 < 32; ci2++) {
            float4 q = wv[ci2];
            float a0 = u[2 * ci2], a1 = u[2 * ci2 + 1];
            ax = __builtin_fmaf(q.x, a0, ax); ax = __builtin_fmaf(q.z, a1, ax);
            ay = __builtin_fmaf(q.y, a0, ay); ay = __builtin_fmaf(q.w, a1, ay);
        }
        f[2 * co2] = ax; f[2 * co2 + 1] = ay;
    }

    float2 oo[5];
#pragma unroll
    for (int oc2 = 0; oc2 < 5; oc2++) oo[oc2] = make_float2(F3B[2 * oc2], F3B[2 * oc2 + 1]);
#pragma unroll 1
    for (int m2 = 0; m2 < 16; m2++) {
        float ax = F2B[2 * m2], ay = F2B[2 * m2 + 1];
        const float4* wv = F2W + m2 * 32;
#pragma unroll
        for (int ch2 = 0; ch2 < 32; ch2++) {
            float4 q = wv[ch2];
            ax = __builtin_fmaf(q.x, f[2 * ch2], ax); ax = __builtin_fmaf(q.z, f[2 * ch2 + 1], ax);
            ay = __builtin_fmaf(q.y, f[2 * ch2], ay); ay = __builtin_fmaf(q.w, f[2 * ch2 + 1], ay);
        }
        ax = fmaxf(ax, 0.f); ay = fmaxf(ay, 0.f);
#pragma unroll
        for (int oc2 = 0; oc2 < 5; oc2++) {
            float4 q = F3W[oc2 * 16 + m2];
            oo[oc2].x += q.x * ax + q.z * ay;
            oo[oc2].y += q.y * ax + q.w * ay;
        }
    }
    float* ob = out + (size_t)b * OUTC * NPIX + pix;
#pragma unroll
    for (int oc2 = 0; oc2 < 5; oc2++) {
        ob[(size_t)(2 * oc2) * NPIX]     = oo[oc2].x;
        ob[(size_t)(2 * oc2 + 1) * NPIX] = oo[oc2].y;
    }
}

extern "C" void kernel_launch(void* const* d_in, const int* in_sizes, int n_in,
                              void* d_out, int out_size, void* d_ws, size_t ws_size,
                              hipStream_t stream) {
    const float* x     = (const float*)d_in[0];
    const float* eattr = (const float*)d_in[3];
    const float* Wih0  = (const float*)d_in[4];
    const float* Whh0  = (const float*)d_in[5];
    const float* bih0  = (const float*)d_in[6];
    const float* bhh0  = (const float*)d_in[7];
    const float* Wih1  = (const float*)d_in[8];
    const float* Whh1  = (const float*)d_in[9];
    const float* bih1  = (const float*)d_in[10];
    const float* bhh1  = (const float*)d_in[11];
    const float* fc1w  = (const float*)d_in[12];
    const float* fc1b  = (const float*)d_in[13];
    const float* convw = (const float*)d_in[14];
    const float* convb = (const float*)d_in[15];
    const float* gparam= (const float*)d_in[16];
    const float* fc2w  = (const float*)d_in[17];
    const float* fc2b  = (const float*)d_in[18];
    const float* fc3w  = (const float*)d_in[19];
    const float* fc3b  = (const float*)d_in[20];

    float* P  = (float*)d_ws;
    float* FA = P + OFF_FEATS_A;
    float* FB = P + OFF_FEATS_B;

    prep_kernel<<<64, 256, 0, stream>>>(Wih0, Whh0, bih0, bhh0, Wih1, Whh1, bih1, bhh1,
                                        fc1w, fc1b, convw, convb, fc2w, fc2b, fc3w, fc3b,
                                        gparam, eattr, P);
    lstm_fc1_kernel<<<2048, 256, 0, stream>>>(x, P, FA);
    conv_fused_kernel<<<512, 256, 0, stream>>>(FA, FB, P, 0);
    conv_fused_kernel<<<512, 256, 0, stream>>>(FB, FA, P, 1);
    conv_fused_kernel<<<512, 256, 0, stream>>>(FA, FB, P, 2);
    conv_head_kernel<<<512, 256, 0, stream>>>(FB, P, (float*)d_out);
}